// Round 1
// baseline (284.864 us; speedup 1.0000x reference)
//
#include <hip/hip_runtime.h>
#include <cstdint>
#include <cstddef>

#define NPTS 8192
#define NUM_CLASSES 5
#define XCOLS 10          // 3 coords + batch + feat + 5 seg
#define EPS2 225.0f
#define MIN_PTS 5
#define NGROUPS 10
#define NW 128            // 64-bit words per adjacency row (8192/64)
#define SENT NPTS
#define BIGC 0x3fffffff
#define PROP_ITERS 26

// ---------------- setup: pack coords+p2, compute group ----------------
__global__ void k_setup(const float* __restrict__ x,
                        float4* __restrict__ q, int* __restrict__ grp) {
    int i = blockIdx.x * blockDim.x + threadIdx.x;
    if (i >= NPTS) return;
    const float* r = x + (size_t)i * XCOLS;
    float px = r[0], py = r[1], pz = r[2];
    int b = (int)r[3];
    float best = r[5]; int bc = 0;
    #pragma unroll
    for (int c = 1; c < NUM_CLASSES; c++) {
        float v = r[5 + c];
        if (v > best) { best = v; bc = c; }   // strict > keeps first max (jnp.argmax)
    }
    q[i] = make_float4(px, py, pz, px*px + py*py + pz*pz);
    grp[i] = b * NUM_CLASSES + bc;
}

// ---------------- adjacency bitmask + degree + label init ----------------
// one wave (64 lanes) per row i
__global__ void __launch_bounds__(256) k_adj(
        const float4* __restrict__ q, const int* __restrict__ grp,
        unsigned long long* __restrict__ adj,
        int* __restrict__ core, int* __restrict__ lab) {
    int wave = (blockIdx.x * blockDim.x + threadIdx.x) >> 6;
    int lane = threadIdx.x & 63;
    int i = wave;
    if (i >= NPTS) return;
    float4 qi = q[i];
    int gi = grp[i];
    int deg = 0;
    for (int w = 0; w < NW; w++) {
        int j = w * 64 + lane;
        float4 qj = q[j];
        int gj = grp[j];
        float d2 = qi.w + qj.w - 2.0f * (qi.x*qj.x + qi.y*qj.y + qi.z*qj.z);
        bool a = (gi == gj) && (d2 < EPS2);
        unsigned long long m = __ballot(a);
        if (lane == 0) adj[(size_t)i * NW + w] = m;
        deg += a ? 1 : 0;
    }
    #pragma unroll
    for (int off = 32; off > 0; off >>= 1) deg += __shfl_down(deg, off);
    if (lane == 0) {
        int c = (deg >= MIN_PTS) ? 1 : 0;
        core[i] = c;
        lab[i] = c ? i : SENT;
    }
}

// ---------------- min-label propagation (one wave per core row) ----------------
__global__ void __launch_bounds__(256) k_prop(
        const unsigned long long* __restrict__ adj,
        const int* __restrict__ core, int* __restrict__ lab) {
    int wave = (blockIdx.x * blockDim.x + threadIdx.x) >> 6;
    int lane = threadIdx.x & 63;
    int i = wave;
    if (i >= NPTS) return;
    if (!core[i]) return;              // uniform across the wave
    int m = SENT;
    #pragma unroll
    for (int wh = 0; wh < 2; wh++) {
        int w = lane + wh * 64;
        unsigned long long bits = adj[(size_t)i * NW + w];
        int base = w * 64;
        while (bits) {
            int b = __ffsll((long long)bits) - 1;
            bits &= bits - 1;
            int lj = lab[base + b];    // non-core rows hold SENT -> implicit core filter
            m = (lj < m) ? lj : m;
        }
    }
    #pragma unroll
    for (int off = 32; off > 0; off >>= 1) {
        int o = __shfl_down(m, off);
        m = (o < m) ? o : m;
    }
    if (lane == 0) {
        if (m < SENT) {
            int m2 = lab[m]; m = (m2 < m) ? m2 : m;  // pointer jump 1
            m2 = lab[m];     m = (m2 < m) ? m2 : m;  // pointer jump 2
        }
        lab[i] = m;   // monotone decreasing; self-bit guarantees m <= old lab[i]
    }
}

// ---------------- per-group rank of representatives ----------------
// one wave per group (blockIdx.x = group id)
__global__ void k_rank(const int* __restrict__ grp, const int* __restrict__ core,
                       const int* __restrict__ lab, int* __restrict__ cidrep) {
    int g = blockIdx.x;
    int lane = threadIdx.x;
    int running = 0;
    for (int w = 0; w < NW; w++) {
        int j = w * 64 + lane;
        bool isr = core[j] && (lab[j] == j) && (grp[j] == g);
        unsigned long long mask = __ballot(isr);
        if (isr) {
            unsigned long long below = mask & ((1ull << lane) - 1ull);
            cidrep[j] = running + __popcll(below);
        }
        running += __popcll(mask);
    }
}

// ---------------- ccid: cluster id of each core point (BIG for non-core) ----------------
__global__ void k_ccid(const int* __restrict__ core, const int* __restrict__ lab,
                       const int* __restrict__ cidrep, int* __restrict__ ccid) {
    int i = blockIdx.x * blockDim.x + threadIdx.x;
    if (i >= NPTS) return;
    ccid[i] = core[i] ? cidrep[lab[i]] : BIGC;
}

// ---------------- final labels + clustered output ----------------
// one wave per row
__global__ void __launch_bounds__(256) k_final(
        const unsigned long long* __restrict__ adj,
        const int* __restrict__ core, const int* __restrict__ ccid,
        const float* __restrict__ x, float* __restrict__ out) {
    int wave = (blockIdx.x * blockDim.x + threadIdx.x) >> 6;
    int lane = threadIdx.x & 63;
    int i = wave;
    if (i >= NPTS) return;
    int m = BIGC;
    #pragma unroll
    for (int wh = 0; wh < 2; wh++) {
        int w = lane + wh * 64;
        unsigned long long bits = adj[(size_t)i * NW + w];
        int base = w * 64;
        while (bits) {
            int b = __ffsll((long long)bits) - 1;
            bits &= bits - 1;
            int cj = ccid[base + b];
            m = (cj < m) ? cj : m;
        }
    }
    #pragma unroll
    for (int off = 32; off > 0; off >>= 1) {
        int o = __shfl_down(m, off);
        m = (o < m) ? o : m;
    }
    if (lane == 0) {
        int label = core[i] ? ccid[i] : ((m < BIGC) ? m : -1);
        out[i] = (float)label;
        const float* r = x + (size_t)i * XCOLS;
        float* o = out + NPTS + (size_t)i * 5;
        bool keep = label >= 0;
        #pragma unroll
        for (int c = 0; c < 5; c++) o[c] = keep ? r[c] : 0.0f;
    }
}

extern "C" void kernel_launch(void* const* d_in, const int* in_sizes, int n_in,
                              void* d_out, int out_size, void* d_ws, size_t ws_size,
                              hipStream_t stream) {
    const float* x = (const float*)d_in[0];
    float* out = (float*)d_out;
    char* ws = (char*)d_ws;

    // workspace layout (~8.3 MB total)
    float4* q    = (float4*)(ws);                         // 8192*16 = 131072
    int* grp     = (int*)(ws + 131072);                   // 32768
    int* core    = (int*)(ws + 163840);                   // 32768
    int* lab     = (int*)(ws + 196608);                   // 32768
    int* cidrep  = (int*)(ws + 229376);                   // 32768
    int* ccid    = (int*)(ws + 262144);                   // 32768
    unsigned long long* adj = (unsigned long long*)(ws + 294912);  // 8 MB

    k_setup<<<NPTS / 256, 256, 0, stream>>>(x, q, grp);
    k_adj<<<NPTS / 4, 256, 0, stream>>>(q, grp, adj, core, lab);   // 4 waves/block
    for (int it = 0; it < PROP_ITERS; ++it)
        k_prop<<<NPTS / 4, 256, 0, stream>>>(adj, core, lab);
    k_rank<<<NGROUPS, 64, 0, stream>>>(grp, core, lab, cidrep);
    k_ccid<<<NPTS / 256, 256, 0, stream>>>(core, lab, cidrep, ccid);
    k_final<<<NPTS / 4, 256, 0, stream>>>(adj, core, ccid, x, out);
}